// Round 3
// baseline (517.848 us; speedup 1.0000x reference)
//
#include <hip/hip_runtime.h>
#include <hip/hip_bf16.h>
#include <math.h>

#define R_CNT   20000
#define L_CNT   30
#define D_CNT   200
#define A_CNT   32
#define B_CNT   4096
#define NNZ_CNT 65536
#define AVG_RATING 3.8f

// ---- d_out layout (floats) ----
#define OUT_OBJ  0
#define OUT_RL   1
#define OUT_AB   (1 + B_CNT)               // 4097
#define OUT_PRED (OUT_AB + 2*R_CNT)        // 44097
#define OUT_UA   (OUT_PRED + B_CNT)        // 48193
#define OUT_IA   (OUT_UA + B_CNT*A_CNT)    // 179265

// ---- ws layout (bytes) ----
#define WS_DBL    0        // double[4]: 0=J_sum, 1=S_sum, 2=rating_sum
#define WS_ULOSS  32       // float
#define WS_MODE   36       // int (1 => indices are int64 in memory)
#define WS_FMLIN  64       // float[4096]
#define WS_PT     16448    // float[R*32]
#define WS_V      2576448  // float[R*200]

// Block-wide reduction of 4 channels across 256 threads (4 waves of 64).
__device__ __forceinline__ float4 blk_reduce4(float4 v, float4* scratch) {
    __syncthreads();  // protect scratch reuse across calls
    #pragma unroll
    for (int o = 32; o >= 1; o >>= 1) {
        v.x += __shfl_xor(v.x, o);
        v.y += __shfl_xor(v.y, o);
        v.z += __shfl_xor(v.z, o);
        v.w += __shfl_xor(v.w, o);
    }
    int w = threadIdx.x >> 6;
    if ((threadIdx.x & 63) == 0) scratch[w] = v;
    __syncthreads();
    float4 t0 = scratch[0], t1 = scratch[1], t2 = scratch[2], t3 = scratch[3];
    return make_float4(t0.x + t1.x + t2.x + t3.x,
                       t0.y + t1.y + t2.y + t3.y,
                       t0.z + t1.z + t2.z + t3.z,
                       t0.w + t1.w + t2.w + t3.w);
}

// ---- K_init: zero accumulators + user/item aspect outputs, detect index dtype ----
__global__ __launch_bounds__(256) void k_init(float* __restrict__ out,
                                              double* __restrict__ dbl,
                                              float* __restrict__ uloss,
                                              int* __restrict__ mode,
                                              const int* __restrict__ u_idx) {
    int gid = blockIdx.x * 256 + threadIdx.x;
    if (gid < 2 * B_CNT * A_CNT) out[OUT_UA + gid] = 0.f;
    if (gid == 0) {
        dbl[0] = 0.0; dbl[1] = 0.0; dbl[2] = 0.0;
        *uloss = 0.f;
        // If the backing store is int64, every odd int32 is a zero high-word.
        int m = 1;
        for (int i = 1; i < 256; i += 2) if (u_idx[i] != 0) { m = 0; break; }
        *mode = m;
    }
}

// ---- K_uloss: orthogonality regularizer on T_w columns (tiny, 1 block) ----
__global__ __launch_bounds__(256) void k_uloss(const float* __restrict__ T_w,
                                               float* __restrict__ uloss) {
    __shared__ float tn[32];
    __shared__ float4 red4[4];
    int tid = threadIdx.x;
    int a = tid >> 3, k = tid & 7;
    float p = 0.f;
    for (int d = k; d < D_CNT; d += 8) { float t = T_w[d*32 + a]; p = fmaf(t, t, p); }
    p += __shfl_xor(p, 1); p += __shfl_xor(p, 2); p += __shfl_xor(p, 4);
    if (k == 0) tn[a] = fmaxf(sqrtf(p), 1e-12f);
    __syncthreads();
    float local = 0.f;
    for (int t = 0; t < 4; t++) {
        int e = tid + 256 * t;
        int i = e >> 5, j = e & 31;
        float s = 0.f;
        for (int d = 0; d < D_CNT; d++) s = fmaf(T_w[d*32 + i], T_w[d*32 + j], s);
        float g = s / (tn[i] * tn[j]);
        float diff = g - ((i == j) ? 1.f : 0.f);
        local += diff * diff;
    }
    float4 tot = blk_reduce4(make_float4(local, 0.f, 0.f, 0.f), red4);
    if (tid == 0) *uloss = tot.x / 1024.f;
}

// ---- K_vgemm: V = Y_s (R x 200) @ M_w (200 x 200) ----
// 64 rows x 200 cols per block (cols zero-padded to 256), 8x8 register tile.
__global__ __launch_bounds__(256) void k_vgemm(const float* __restrict__ y_s,
                                               const float* __restrict__ M_w,
                                               float* __restrict__ V) {
    __shared__ __align__(16) float Msh[25 * 260];  // [ee][d(pad 260)]
    __shared__ __align__(16) float Ysh[25 * 68];   // [ee][rr(pad 68)]
    int tid = threadIdx.x;
    int r0 = blockIdx.x * 64;
    int dg = tid & 31, rg = tid >> 5;
    float acc[8][8];
    #pragma unroll
    for (int i = 0; i < 8; i++)
        #pragma unroll
        for (int j = 0; j < 8; j++) acc[i][j] = 0.f;

    for (int e0 = 0; e0 < D_CNT; e0 += 25) {
        __syncthreads();
        for (int idx = tid; idx < 25 * 256; idx += 256) {
            int ee = idx >> 8, d = idx & 255;
            Msh[ee * 260 + d] = (d < D_CNT) ? M_w[(e0 + ee) * D_CNT + d] : 0.f;
        }
        for (int idx = tid; idx < 25 * 64; idx += 256) {
            int rr = idx / 25, ee = idx - rr * 25;
            int row = r0 + rr;
            Ysh[ee * 68 + rr] = (row < R_CNT) ? y_s[row * D_CNT + e0 + ee] : 0.f;
        }
        __syncthreads();
        for (int ee = 0; ee < 25; ee++) {
            const float4 ya = *(const float4*)&Ysh[ee * 68 + rg * 8];
            const float4 yb = *(const float4*)&Ysh[ee * 68 + rg * 8 + 4];
            const float4 ma = *(const float4*)&Msh[ee * 260 + dg * 8];
            const float4 mb = *(const float4*)&Msh[ee * 260 + dg * 8 + 4];
            float ys[8] = {ya.x, ya.y, ya.z, ya.w, yb.x, yb.y, yb.z, yb.w};
            float ms[8] = {ma.x, ma.y, ma.z, ma.w, mb.x, mb.y, mb.z, mb.w};
            #pragma unroll
            for (int i = 0; i < 8; i++)
                #pragma unroll
                for (int j = 0; j < 8; j++)
                    acc[i][j] = fmaf(ys[i], ms[j], acc[i][j]);
        }
    }
    if (dg < 25) {
        #pragma unroll
        for (int i = 0; i < 8; i++) {
            int row = r0 + rg * 8 + i;
            if (row < R_CNT) {
                *(float4*)&V[row * D_CNT + dg * 8]     = make_float4(acc[i][0], acc[i][1], acc[i][2], acc[i][3]);
                *(float4*)&V[row * D_CNT + dg * 8 + 4] = make_float4(acc[i][4], acc[i][5], acc[i][6], acc[i][7]);
            }
        }
    }
}

// ---- K_main: per-review ABAE pipeline (one block per review) ----
__global__ __launch_bounds__(256) void k_main(
    const float* __restrict__ e_w, const float* __restrict__ y_s,
    const float* __restrict__ z_n, const float* __restrict__ M_b,
    const float* __restrict__ W_w, const float* __restrict__ W_b,
    const float* __restrict__ T_w, const float* __restrict__ T_b,
    const float* __restrict__ V, float* __restrict__ p_t,
    float* __restrict__ out, double* __restrict__ j_sum) {
    __shared__ __align__(16) float ew[L_CNT * D_CNT];  // 6000 floats
    __shared__ float vsh[D_CNT], ysh[D_CNT], zsh[D_CNT], rsh[D_CNT];
    __shared__ float axs[32], pts[32];
    __shared__ float4 red4[4];
    int r = blockIdx.x, tid = threadIdx.x;

    // stage e_w[r] (24 KB) + v[r] + y_s[r]
    const float4* src = (const float4*)(e_w + (size_t)r * 6000);
    float4* dst = (float4*)ew;
    for (int i = tid; i < 1500; i += 256) dst[i] = src[i];
    if (tid < D_CNT) { vsh[tid] = V[r * D_CNT + tid]; ysh[tid] = y_s[r * D_CNT + tid]; }
    __syncthreads();

    // bias = M_b . y_s[r]
    float pb = (tid < D_CNT) ? M_b[tid] * ysh[tid] : 0.f;
    float bias = blk_reduce4(make_float4(pb, 0.f, 0.f, 0.f), red4).x;

    // dx[l] = e_w[r,l,:].v + bias  (30 groups of 8 lanes)
    if (tid < 240) {
        int l = tid >> 3, k = tid & 7;
        float p = 0.f;
        for (int j = k; j < D_CNT; j += 8) p = fmaf(ew[l * D_CNT + j], vsh[j], p);
        p += __shfl_xor(p, 1); p += __shfl_xor(p, 2); p += __shfl_xor(p, 4);
        if (k == 0) axs[l] = p + bias;
    }
    __syncthreads();

    // softmax over L=30 (first wave)
    if (tid < 64) {
        float v = (tid < L_CNT) ? axs[tid] : -1e30f;
        float m = v;
        #pragma unroll
        for (int o = 32; o >= 1; o >>= 1) m = fmaxf(m, __shfl_xor(m, o));
        float e = (tid < L_CNT) ? expf(v - m) : 0.f;
        float s = e;
        #pragma unroll
        for (int o = 32; o >= 1; o >>= 1) s += __shfl_xor(s, o);
        if (tid < L_CNT) axs[tid] = e / s;
    }
    __syncthreads();

    // z_s[d] = sum_l e_w[l,d] * ax[l]
    if (tid < D_CNT) {
        float z = 0.f;
        #pragma unroll
        for (int l = 0; l < L_CNT; l++) z = fmaf(ew[l * D_CNT + tid], axs[l], z);
        zsh[tid] = z;
    }
    __syncthreads();

    // p_t[a] = z_s . W_w[a,:] + W_b[a]   (32 groups of 8 lanes)
    {
        int a = tid >> 3, k = tid & 7;
        float p = 0.f;
        for (int j = k; j < D_CNT; j += 8) p = fmaf(zsh[j], W_w[a * D_CNT + j], p);
        p += __shfl_xor(p, 1); p += __shfl_xor(p, 2); p += __shfl_xor(p, 4);
        if (k == 0) {
            float pt = p + W_b[a];
            pts[a] = pt;
            p_t[r * 32 + a] = pt;
        }
    }
    __syncthreads();

    // r_s[d] = sum_a p_t[a]*T_w[d,a] + T_b[d]
    if (tid < D_CNT) {
        float rv = T_b[tid];
        const float4* tw = (const float4*)(T_w + tid * 32);
        #pragma unroll
        for (int q = 0; q < 8; q++) {
            float4 t = tw[q];
            rv = fmaf(t.x, pts[q * 4 + 0], rv);
            rv = fmaf(t.y, pts[q * 4 + 1], rv);
            rv = fmaf(t.z, pts[q * 4 + 2], rv);
            rv = fmaf(t.w, pts[q * 4 + 3], rv);
        }
        rsh[tid] = rv;
    }
    __syncthreads();

    float rv = (tid < D_CNT) ? rsh[tid] : 0.f;
    float zv = (tid < D_CNT) ? zsh[tid] : 0.f;
    float4 s3 = blk_reduce4(make_float4(rv * rv, rv * zv, zv * zv, 0.f), red4);
    float nr = fmaxf(sqrtf(s3.x), 1e-12f);
    float nz = fmaxf(sqrtf(s3.z), 1e-12f);
    float c1 = s3.y / (nr * nz);

    float zn0 = (tid < D_CNT) ? z_n[(size_t)(2 * r) * D_CNT + tid] : 0.f;
    float zn1 = (tid < D_CNT) ? z_n[(size_t)(2 * r + 1) * D_CNT + tid] : 0.f;
    float4 s4 = blk_reduce4(make_float4(zn0 * zn0, zn0 * rv, zn1 * zn1, zn1 * rv), red4);
    float c20 = s4.y / (fmaxf(sqrtf(s4.x), 1e-12f) * nr);
    float c21 = s4.w / (fmaxf(sqrtf(s4.z), 1e-12f) * nr);
    float l0 = fmaxf(0.f, 1.f - (c1 - c20));
    float l1 = fmaxf(0.f, 1.f - (c1 - c21));
    if (tid == 0) {
        out[OUT_AB + 2 * r]     = l0;
        out[OUT_AB + 2 * r + 1] = l1;
        atomicAdd(j_sum, (double)l0 + (double)l1);
    }
}

// ---- K_scatter: user/item aspect segment sums via atomics ----
__global__ __launch_bounds__(256) void k_scatter(const int* __restrict__ u_idx,
                                                 const int* __restrict__ i_idx,
                                                 const float* __restrict__ u_val,
                                                 const float* __restrict__ i_val,
                                                 const float* __restrict__ p_t,
                                                 const int* __restrict__ mode,
                                                 float* __restrict__ out) {
    long long gid = (long long)blockIdx.x * 256 + threadIdx.x;
    const long long HALF = (long long)NNZ_CNT * 32;
    int is_item = gid >= HALF;
    long long rem = gid - (is_item ? HALF : 0);
    int k = (int)(rem >> 5), a = (int)(rem & 31);
    const int* idx = is_item ? i_idx : u_idx;
    const float* val = is_item ? i_val : u_val;
    int m64 = *mode;
    int row, col;
    if (m64) { row = idx[2 * k]; col = idx[2 * (NNZ_CNT + k)]; }
    else     { row = idx[k];     col = idx[NNZ_CNT + k]; }
    float v = p_t[col * 32 + a] * val[k];
    float* base = out + (is_item ? OUT_IA : OUT_UA);
    atomicAdd(&base[row * 32 + a], v);
}

// ---- K_fm: factorization machine per-b terms + global scalar S ----
__global__ __launch_bounds__(256) void k_fm(const float* __restrict__ out,
                                            const float* __restrict__ fc_w,
                                            const float* __restrict__ fc_b,
                                            const float* __restrict__ fm_V,
                                            float* __restrict__ fm_lin,
                                            double* __restrict__ s_sum) {
    int tid = threadIdx.x;
    int a = tid & 31;
    int b = blockIdx.x * 8 + (tid >> 5);
    float ua = out[OUT_UA + b * 32 + a];
    float ia = out[OUT_IA + b * 32 + a];
    float oe = ua * ia;
    float oe2 = oe * oe;
    float lin = oe * fc_w[a];
    #pragma unroll
    for (int o = 1; o < 32; o <<= 1) lin += __shfl_xor(lin, o);
    float part = 0.f;
    #pragma unroll
    for (int j = 0; j < 10; j++) {
        float v = fm_V[a * 10 + j];
        float s1 = oe * v;
        float s2 = oe2 * v * v;
        #pragma unroll
        for (int o = 1; o < 32; o <<= 1) { s1 += __shfl_xor(s1, o); s2 += __shfl_xor(s2, o); }
        part += s1 * s1 - s2;
    }
    if (a == 0) {
        fm_lin[b] = lin + fc_b[0];
        atomicAdd(s_sum, 0.5 * (double)part);
    }
}

// ---- K_pred: predictions + rating losses + rating_sum ----
__global__ __launch_bounds__(256) void k_pred(const float* __restrict__ label,
                                              const float* __restrict__ fm_lin,
                                              const double* __restrict__ s_sum,
                                              float* __restrict__ out,
                                              double* __restrict__ r_sum) {
    __shared__ float4 red4[4];
    int b = blockIdx.x * 256 + threadIdx.x;
    float S = (float)(*s_sum);
    float pred = fm_lin[b] + S + AVG_RATING;
    float d = pred - label[b];
    float rl = d * d;
    out[OUT_PRED + b] = pred;
    out[OUT_RL + b] = rl;
    float4 t = blk_reduce4(make_float4(rl, 0.f, 0.f, 0.f), red4);
    if (threadIdx.x == 0) atomicAdd(r_sum, (double)t.x);
}

// ---- K_final: assemble scalar objective ----
__global__ void k_final(const double* __restrict__ dbl,
                        const float* __restrict__ uloss,
                        float* __restrict__ out) {
    if (threadIdx.x == 0) {
        double J = dbl[0] / (2.0 * R_CNT);
        double RL = dbl[2] / (double)B_CNT;
        out[OUT_OBJ] = (float)(RL + (double)(*uloss) + J);
    }
}

extern "C" void kernel_launch(void* const* d_in, const int* in_sizes, int n_in,
                              void* d_out, int out_size, void* d_ws, size_t ws_size,
                              hipStream_t stream) {
    const float* e_w   = (const float*)d_in[0];
    const float* y_s   = (const float*)d_in[1];
    const float* z_n   = (const float*)d_in[2];
    const float* label = (const float*)d_in[3];
    const float* u_val = (const float*)d_in[4];
    const float* i_val = (const float*)d_in[5];
    const float* M_w   = (const float*)d_in[6];
    const float* M_b   = (const float*)d_in[7];
    const float* W_w   = (const float*)d_in[8];
    const float* W_b   = (const float*)d_in[9];
    const float* T_w   = (const float*)d_in[10];
    const float* T_b   = (const float*)d_in[11];
    const float* fc_w  = (const float*)d_in[12];
    const float* fc_b  = (const float*)d_in[13];
    const float* fm_V  = (const float*)d_in[14];
    const int*   u_idx = (const int*)d_in[15];
    const int*   i_idx = (const int*)d_in[16];

    float* out = (float*)d_out;
    char* ws = (char*)d_ws;
    double* dbl   = (double*)(ws + WS_DBL);
    float* uloss  = (float*)(ws + WS_ULOSS);
    int* mode     = (int*)(ws + WS_MODE);
    float* fm_lin = (float*)(ws + WS_FMLIN);
    float* p_t    = (float*)(ws + WS_PT);
    float* V      = (float*)(ws + WS_V);

    k_init<<<(2 * B_CNT * A_CNT) / 256, 256, 0, stream>>>(out, dbl, uloss, mode, u_idx);
    k_uloss<<<1, 256, 0, stream>>>(T_w, uloss);
    k_vgemm<<<(R_CNT + 63) / 64, 256, 0, stream>>>(y_s, M_w, V);
    k_main<<<R_CNT, 256, 0, stream>>>(e_w, y_s, z_n, M_b, W_w, W_b, T_w, T_b,
                                      V, p_t, out, &dbl[0]);
    k_scatter<<<(2 * NNZ_CNT * 32) / 256, 256, 0, stream>>>(u_idx, i_idx, u_val, i_val,
                                                            p_t, mode, out);
    k_fm<<<B_CNT / 8, 256, 0, stream>>>(out, fc_w, fc_b, fm_V, fm_lin, &dbl[1]);
    k_pred<<<B_CNT / 256, 256, 0, stream>>>(label, fm_lin, &dbl[1], out, &dbl[2]);
    k_final<<<1, 64, 0, stream>>>(dbl, uloss, out);
}

// Round 4
// 494.003 us; speedup vs baseline: 1.0483x; 1.0483x over previous
//
#include <hip/hip_runtime.h>
#include <hip/hip_bf16.h>
#include <math.h>

#define R_CNT   20000
#define L_CNT   30
#define D_CNT   200
#define A_CNT   32
#define B_CNT   4096
#define NNZ_CNT 65536
#define AVG_RATING 3.8f

// ---- d_out layout (floats) ----
#define OUT_OBJ  0
#define OUT_RL   1
#define OUT_AB   (1 + B_CNT)               // 4097
#define OUT_PRED (OUT_AB + 2*R_CNT)        // 44097
#define OUT_UA   (OUT_PRED + B_CNT)        // 48193
#define OUT_IA   (OUT_UA + B_CNT*A_CNT)    // 179265

// ---- ws layout (bytes) ----
#define WS_DBL    0        // double[4]: 0=J_sum, 1=S_sum, 2=rating_sum
#define WS_ULOSS  32       // float
#define WS_MODE   36       // int (1 => indices are int64 in memory)
#define WS_FMLIN  64       // float[4096]
#define WS_PT     16448    // float[R*32]
#define WS_V      2576448  // float[R*200]

// Block-wide reduction of 4 channels across 256 threads (4 waves of 64).
__device__ __forceinline__ float4 blk_reduce4(float4 v, float4* scratch) {
    __syncthreads();  // protect scratch reuse across calls
    #pragma unroll
    for (int o = 32; o >= 1; o >>= 1) {
        v.x += __shfl_xor(v.x, o);
        v.y += __shfl_xor(v.y, o);
        v.z += __shfl_xor(v.z, o);
        v.w += __shfl_xor(v.w, o);
    }
    int w = threadIdx.x >> 6;
    if ((threadIdx.x & 63) == 0) scratch[w] = v;
    __syncthreads();
    float4 t0 = scratch[0], t1 = scratch[1], t2 = scratch[2], t3 = scratch[3];
    return make_float4(t0.x + t1.x + t2.x + t3.x,
                       t0.y + t1.y + t2.y + t3.y,
                       t0.z + t1.z + t2.z + t3.z,
                       t0.w + t1.w + t2.w + t3.w);
}

// ---- K_init: zero accumulators + user/item aspect outputs, detect index dtype ----
__global__ __launch_bounds__(256) void k_init(float* __restrict__ out,
                                              double* __restrict__ dbl,
                                              float* __restrict__ uloss,
                                              int* __restrict__ mode,
                                              const int* __restrict__ u_idx) {
    int gid = blockIdx.x * 256 + threadIdx.x;
    if (gid < 2 * B_CNT * A_CNT) out[OUT_UA + gid] = 0.f;
    if (gid == 0) {
        dbl[0] = 0.0; dbl[1] = 0.0; dbl[2] = 0.0;
        *uloss = 0.f;
        // If the backing store is int64, every odd int32 is a zero high-word.
        int m = 1;
        for (int i = 1; i < 256; i += 2) if (u_idx[i] != 0) { m = 0; break; }
        *mode = m;
    }
}

// ---- K_uloss: orthogonality regularizer on T_w columns (tiny, 1 block) ----
__global__ __launch_bounds__(256) void k_uloss(const float* __restrict__ T_w,
                                               float* __restrict__ uloss) {
    __shared__ float tn[32];
    __shared__ float4 red4[4];
    int tid = threadIdx.x;
    int a = tid >> 3, k = tid & 7;
    float p = 0.f;
    for (int d = k; d < D_CNT; d += 8) { float t = T_w[d*32 + a]; p = fmaf(t, t, p); }
    p += __shfl_xor(p, 1); p += __shfl_xor(p, 2); p += __shfl_xor(p, 4);
    if (k == 0) tn[a] = fmaxf(sqrtf(p), 1e-12f);
    __syncthreads();
    float local = 0.f;
    for (int t = 0; t < 4; t++) {
        int e = tid + 256 * t;
        int i = e >> 5, j = e & 31;
        float s = 0.f;
        for (int d = 0; d < D_CNT; d++) s = fmaf(T_w[d*32 + i], T_w[d*32 + j], s);
        float g = s / (tn[i] * tn[j]);
        float diff = g - ((i == j) ? 1.f : 0.f);
        local += diff * diff;
    }
    float4 tot = blk_reduce4(make_float4(local, 0.f, 0.f, 0.f), red4);
    if (tid == 0) *uloss = tot.x / 1024.f;
}

// ---- K_vgemm: V = Y_s (R x 200) @ M_w (200 x 200) ----
// 64 rows x 200 cols per block (cols zero-padded to 256), 8x8 register tile.
__global__ __launch_bounds__(256) void k_vgemm(const float* __restrict__ y_s,
                                               const float* __restrict__ M_w,
                                               float* __restrict__ V) {
    __shared__ __align__(16) float Msh[25 * 260];  // [ee][d(pad 260)]
    __shared__ __align__(16) float Ysh[25 * 68];   // [ee][rr(pad 68)]
    int tid = threadIdx.x;
    int r0 = blockIdx.x * 64;
    int dg = tid & 31, rg = tid >> 5;
    float acc[8][8];
    #pragma unroll
    for (int i = 0; i < 8; i++)
        #pragma unroll
        for (int j = 0; j < 8; j++) acc[i][j] = 0.f;

    for (int e0 = 0; e0 < D_CNT; e0 += 25) {
        __syncthreads();
        for (int idx = tid; idx < 25 * 256; idx += 256) {
            int ee = idx >> 8, d = idx & 255;
            Msh[ee * 260 + d] = (d < D_CNT) ? M_w[(e0 + ee) * D_CNT + d] : 0.f;
        }
        for (int idx = tid; idx < 25 * 64; idx += 256) {
            int rr = idx / 25, ee = idx - rr * 25;
            int row = r0 + rr;
            Ysh[ee * 68 + rr] = (row < R_CNT) ? y_s[row * D_CNT + e0 + ee] : 0.f;
        }
        __syncthreads();
        for (int ee = 0; ee < 25; ee++) {
            const float4 ya = *(const float4*)&Ysh[ee * 68 + rg * 8];
            const float4 yb = *(const float4*)&Ysh[ee * 68 + rg * 8 + 4];
            const float4 ma = *(const float4*)&Msh[ee * 260 + dg * 8];
            const float4 mb = *(const float4*)&Msh[ee * 260 + dg * 8 + 4];
            float ys[8] = {ya.x, ya.y, ya.z, ya.w, yb.x, yb.y, yb.z, yb.w};
            float ms[8] = {ma.x, ma.y, ma.z, ma.w, mb.x, mb.y, mb.z, mb.w};
            #pragma unroll
            for (int i = 0; i < 8; i++)
                #pragma unroll
                for (int j = 0; j < 8; j++)
                    acc[i][j] = fmaf(ys[i], ms[j], acc[i][j]);
        }
    }
    if (dg < 25) {
        #pragma unroll
        for (int i = 0; i < 8; i++) {
            int row = r0 + rg * 8 + i;
            if (row < R_CNT) {
                *(float4*)&V[row * D_CNT + dg * 8]     = make_float4(acc[i][0], acc[i][1], acc[i][2], acc[i][3]);
                *(float4*)&V[row * D_CNT + dg * 8 + 4] = make_float4(acc[i][4], acc[i][5], acc[i][6], acc[i][7]);
            }
        }
    }
}

// ---- K_main: per-review ABAE pipeline (one block per review) ----
// Barrier-minimized: bias dropped (softmax shift-invariance), r_s kept in
// registers, single fused 7-channel loss reduction. LDS 25984 B -> 6 blk/CU.
__global__ __launch_bounds__(256) void k_main(
    const float* __restrict__ e_w, const float* __restrict__ z_n,
    const float* __restrict__ W_w, const float* __restrict__ W_b,
    const float* __restrict__ T_w, const float* __restrict__ T_b,
    const float* __restrict__ V, float* __restrict__ p_t,
    float* __restrict__ out, double* __restrict__ j_sum) {
    __shared__ __align__(16) float ew[L_CNT * D_CNT];  // 6000 floats = 24000 B
    __shared__ __align__(16) float vsh[D_CNT];         // 800 B
    __shared__ __align__(16) float zsh[D_CNT];         // 800 B
    __shared__ float axs[32], pts[32];                 // 256 B
    __shared__ float4 red[8];                          // 128 B
    int r = blockIdx.x, tid = threadIdx.x;

    // Early independent loads: z_n rows for this review (hide HBM latency
    // under the e_w staging + compute chain).
    float zn0 = (tid < D_CNT) ? z_n[(size_t)(2 * r) * D_CNT + tid] : 0.f;
    float zn1 = (tid < D_CNT) ? z_n[(size_t)(2 * r + 1) * D_CNT + tid] : 0.f;

    // stage e_w[r] (24 KB) + v[r]
    const float4* src = (const float4*)(e_w + (size_t)r * 6000);
    float4* dst = (float4*)ew;
    for (int i = tid; i < 1500; i += 256) dst[i] = src[i];
    if (tid < D_CNT) vsh[tid] = V[r * D_CNT + tid];
    __syncthreads();                                   // B1

    // dx[l] = e_w[r,l,:].v   (bias M_b.y_s is constant over l -> cancels in softmax)
    if (tid < 240) {
        int l = tid >> 3, k = tid & 7;
        float p = 0.f;
        for (int j = k; j < D_CNT; j += 8) p = fmaf(ew[l * D_CNT + j], vsh[j], p);
        p += __shfl_xor(p, 1); p += __shfl_xor(p, 2); p += __shfl_xor(p, 4);
        if (k == 0) axs[l] = p;
    }
    __syncthreads();                                   // B2

    // softmax over L=30 (first wave)
    if (tid < 64) {
        float v = (tid < L_CNT) ? axs[tid] : -1e30f;
        float m = v;
        #pragma unroll
        for (int o = 32; o >= 1; o >>= 1) m = fmaxf(m, __shfl_xor(m, o));
        float e = (tid < L_CNT) ? __expf(v - m) : 0.f;
        float s = e;
        #pragma unroll
        for (int o = 32; o >= 1; o >>= 1) s += __shfl_xor(s, o);
        if (tid < L_CNT) axs[tid] = e / s;
    }
    __syncthreads();                                   // B3

    // z_s[d] = sum_l e_w[l,d] * ax[l]
    if (tid < D_CNT) {
        float z = 0.f;
        #pragma unroll
        for (int l = 0; l < L_CNT; l++) z = fmaf(ew[l * D_CNT + tid], axs[l], z);
        zsh[tid] = z;
    }
    __syncthreads();                                   // B4

    // p_t[a] = z_s . W_w[a,:] + W_b[a]   (32 groups of 8 lanes)
    {
        int a = tid >> 3, k = tid & 7;
        float p = 0.f;
        for (int j = k; j < D_CNT; j += 8) p = fmaf(zsh[j], W_w[a * D_CNT + j], p);
        p += __shfl_xor(p, 1); p += __shfl_xor(p, 2); p += __shfl_xor(p, 4);
        if (k == 0) {
            float pt = p + W_b[a];
            pts[a] = pt;
            p_t[r * 32 + a] = pt;
        }
    }
    __syncthreads();                                   // B5

    // r_s[d] in-register + fused 7-channel loss reduction
    float rv = 0.f, zv = 0.f;
    if (tid < D_CNT) {
        rv = T_b[tid];
        const float4* tw = (const float4*)(T_w + tid * 32);
        #pragma unroll
        for (int q = 0; q < 8; q++) {
            float4 t = tw[q];
            rv = fmaf(t.x, pts[q * 4 + 0], rv);
            rv = fmaf(t.y, pts[q * 4 + 1], rv);
            rv = fmaf(t.z, pts[q * 4 + 2], rv);
            rv = fmaf(t.w, pts[q * 4 + 3], rv);
        }
        zv = zsh[tid];
    }
    float4 Av = make_float4(rv * rv, rv * zv, zv * zv, zn0 * zn0);
    float4 Bv = make_float4(zn0 * rv, zn1 * zn1, zn1 * rv, 0.f);
    #pragma unroll
    for (int o = 32; o >= 1; o >>= 1) {
        Av.x += __shfl_xor(Av.x, o); Av.y += __shfl_xor(Av.y, o);
        Av.z += __shfl_xor(Av.z, o); Av.w += __shfl_xor(Av.w, o);
        Bv.x += __shfl_xor(Bv.x, o); Bv.y += __shfl_xor(Bv.y, o);
        Bv.z += __shfl_xor(Bv.z, o);
    }
    int w = tid >> 6;
    if ((tid & 63) == 0) { red[2 * w] = Av; red[2 * w + 1] = Bv; }
    __syncthreads();                                   // B6
    if (tid == 0) {
        float rr = 0.f, rz = 0.f, zz = 0.f, n00 = 0.f, n0r = 0.f, n11 = 0.f, n1r = 0.f;
        #pragma unroll
        for (int i = 0; i < 4; i++) {
            float4 a = red[2 * i], b = red[2 * i + 1];
            rr += a.x; rz += a.y; zz += a.z; n00 += a.w;
            n0r += b.x; n11 += b.y; n1r += b.z;
        }
        float nr = fmaxf(sqrtf(rr), 1e-12f);
        float nz = fmaxf(sqrtf(zz), 1e-12f);
        float c1 = rz / (nr * nz);
        float c20 = n0r / (fmaxf(sqrtf(n00), 1e-12f) * nr);
        float c21 = n1r / (fmaxf(sqrtf(n11), 1e-12f) * nr);
        float l0 = fmaxf(0.f, 1.f - (c1 - c20));
        float l1 = fmaxf(0.f, 1.f - (c1 - c21));
        out[OUT_AB + 2 * r]     = l0;
        out[OUT_AB + 2 * r + 1] = l1;
        atomicAdd(j_sum, (double)l0 + (double)l1);
    }
}

// ---- K_scatter: user/item aspect segment sums via atomics ----
__global__ __launch_bounds__(256) void k_scatter(const int* __restrict__ u_idx,
                                                 const int* __restrict__ i_idx,
                                                 const float* __restrict__ u_val,
                                                 const float* __restrict__ i_val,
                                                 const float* __restrict__ p_t,
                                                 const int* __restrict__ mode,
                                                 float* __restrict__ out) {
    long long gid = (long long)blockIdx.x * 256 + threadIdx.x;
    const long long HALF = (long long)NNZ_CNT * 32;
    int is_item = gid >= HALF;
    long long rem = gid - (is_item ? HALF : 0);
    int k = (int)(rem >> 5), a = (int)(rem & 31);
    const int* idx = is_item ? i_idx : u_idx;
    const float* val = is_item ? i_val : u_val;
    int m64 = *mode;
    int row, col;
    if (m64) { row = idx[2 * k]; col = idx[2 * (NNZ_CNT + k)]; }
    else     { row = idx[k];     col = idx[NNZ_CNT + k]; }
    float v = p_t[col * 32 + a] * val[k];
    float* base = out + (is_item ? OUT_IA : OUT_UA);
    atomicAdd(&base[row * 32 + a], v);
}

// ---- K_fm: factorization machine per-b terms + global scalar S ----
__global__ __launch_bounds__(256) void k_fm(const float* __restrict__ out,
                                            const float* __restrict__ fc_w,
                                            const float* __restrict__ fc_b,
                                            const float* __restrict__ fm_V,
                                            float* __restrict__ fm_lin,
                                            double* __restrict__ s_sum) {
    int tid = threadIdx.x;
    int a = tid & 31;
    int b = blockIdx.x * 8 + (tid >> 5);
    float ua = out[OUT_UA + b * 32 + a];
    float ia = out[OUT_IA + b * 32 + a];
    float oe = ua * ia;
    float oe2 = oe * oe;
    float lin = oe * fc_w[a];
    #pragma unroll
    for (int o = 1; o < 32; o <<= 1) lin += __shfl_xor(lin, o);
    float part = 0.f;
    #pragma unroll
    for (int j = 0; j < 10; j++) {
        float v = fm_V[a * 10 + j];
        float s1 = oe * v;
        float s2 = oe2 * v * v;
        #pragma unroll
        for (int o = 1; o < 32; o <<= 1) { s1 += __shfl_xor(s1, o); s2 += __shfl_xor(s2, o); }
        part += s1 * s1 - s2;
    }
    if (a == 0) {
        fm_lin[b] = lin + fc_b[0];
        atomicAdd(s_sum, 0.5 * (double)part);
    }
}

// ---- K_pred: predictions + rating losses + rating_sum ----
__global__ __launch_bounds__(256) void k_pred(const float* __restrict__ label,
                                              const float* __restrict__ fm_lin,
                                              const double* __restrict__ s_sum,
                                              float* __restrict__ out,
                                              double* __restrict__ r_sum) {
    __shared__ float4 red4[4];
    int b = blockIdx.x * 256 + threadIdx.x;
    float S = (float)(*s_sum);
    float pred = fm_lin[b] + S + AVG_RATING;
    float d = pred - label[b];
    float rl = d * d;
    out[OUT_PRED + b] = pred;
    out[OUT_RL + b] = rl;
    float4 t = blk_reduce4(make_float4(rl, 0.f, 0.f, 0.f), red4);
    if (threadIdx.x == 0) atomicAdd(r_sum, (double)t.x);
}

// ---- K_final: assemble scalar objective ----
__global__ void k_final(const double* __restrict__ dbl,
                        const float* __restrict__ uloss,
                        float* __restrict__ out) {
    if (threadIdx.x == 0) {
        double J = dbl[0] / (2.0 * R_CNT);
        double RL = dbl[2] / (double)B_CNT;
        out[OUT_OBJ] = (float)(RL + (double)(*uloss) + J);
    }
}

extern "C" void kernel_launch(void* const* d_in, const int* in_sizes, int n_in,
                              void* d_out, int out_size, void* d_ws, size_t ws_size,
                              hipStream_t stream) {
    const float* e_w   = (const float*)d_in[0];
    const float* y_s   = (const float*)d_in[1];
    const float* z_n   = (const float*)d_in[2];
    const float* label = (const float*)d_in[3];
    const float* u_val = (const float*)d_in[4];
    const float* i_val = (const float*)d_in[5];
    const float* M_w   = (const float*)d_in[6];
    const float* W_w   = (const float*)d_in[8];
    const float* W_b   = (const float*)d_in[9];
    const float* T_w   = (const float*)d_in[10];
    const float* T_b   = (const float*)d_in[11];
    const float* fc_w  = (const float*)d_in[12];
    const float* fc_b  = (const float*)d_in[13];
    const float* fm_V  = (const float*)d_in[14];
    const int*   u_idx = (const int*)d_in[15];
    const int*   i_idx = (const int*)d_in[16];

    float* out = (float*)d_out;
    char* ws = (char*)d_ws;
    double* dbl   = (double*)(ws + WS_DBL);
    float* uloss  = (float*)(ws + WS_ULOSS);
    int* mode     = (int*)(ws + WS_MODE);
    float* fm_lin = (float*)(ws + WS_FMLIN);
    float* p_t    = (float*)(ws + WS_PT);
    float* V      = (float*)(ws + WS_V);

    k_init<<<(2 * B_CNT * A_CNT) / 256, 256, 0, stream>>>(out, dbl, uloss, mode, u_idx);
    k_uloss<<<1, 256, 0, stream>>>(T_w, uloss);
    k_vgemm<<<(R_CNT + 63) / 64, 256, 0, stream>>>(y_s, M_w, V);
    k_main<<<R_CNT, 256, 0, stream>>>(e_w, z_n, W_w, W_b, T_w, T_b,
                                      V, p_t, out, &dbl[0]);
    k_scatter<<<(2 * NNZ_CNT * 32) / 256, 256, 0, stream>>>(u_idx, i_idx, u_val, i_val,
                                                            p_t, mode, out);
    k_fm<<<B_CNT / 8, 256, 0, stream>>>(out, fc_w, fc_b, fm_V, fm_lin, &dbl[1]);
    k_pred<<<B_CNT / 256, 256, 0, stream>>>(label, fm_lin, &dbl[1], out, &dbl[2]);
    k_final<<<1, 64, 0, stream>>>(dbl, uloss, out);
}